// Round 1
// baseline (5217.126 us; speedup 1.0000x reference)
//
#include <hip/hip_runtime.h>
#include <cstddef>

#define Pn 81
#define En 256
#define Hn 4096
#define H4 16384          // 4*Hn
#define KSPLIT 64
#define KC (Hn / KSPLIT)  // 64
#define TT 16             // t-tile for X projection

// ---------------- Mf = W[E:,:] + U   (Hn x H4) ----------------
__global__ __launch_bounds__(256) void fuse_kernel(const float* __restrict__ W,
                                                   const float* __restrict__ U,
                                                   float* __restrict__ Mf) {
    size_t i = (size_t)blockIdx.x * 256 + threadIdx.x;  // float4 index
    const float4* W4 = (const float4*)(W + (size_t)En * H4);
    const float4* U4 = (const float4*)U;
    float4 a = W4[i];
    float4 b = U4[i];
    float4 r;
    r.x = a.x + b.x; r.y = a.y + b.y; r.z = a.z + b.z; r.w = a.w + b.w;
    ((float4*)Mf)[i] = r;
}

// ---------------- X[t] = h_enc[t] @ W[:E] + b   (Pn x H4) ----------------
__global__ __launch_bounds__(256) void xproj_kernel(const float* __restrict__ henc,
                                                    const float* __restrict__ W,
                                                    const float* __restrict__ bias,
                                                    float* __restrict__ X) {
    int col = blockIdx.x * 256 + threadIdx.x;
    int t0  = blockIdx.y * TT;
    __shared__ float hs[TT][En];
    for (int r = threadIdx.x; r < TT * En; r += 256) {
        int tt = r >> 8;       // r / En
        int e  = r & (En - 1); // r % En
        hs[tt][e] = (t0 + tt < Pn) ? henc[(size_t)(t0 + tt) * En + e] : 0.f;
    }
    __syncthreads();
    float acc[TT];
    float bc = bias[col];
#pragma unroll
    for (int tt = 0; tt < TT; ++tt) acc[tt] = bc;
    for (int e = 0; e < En; ++e) {
        float w = W[(size_t)e * H4 + col];
#pragma unroll
        for (int tt = 0; tt < TT; ++tt) acc[tt] += hs[tt][e] * w;
    }
    int nt = Pn - t0; if (nt > TT) nt = TT;
    for (int tt = 0; tt < nt; ++tt) X[(size_t)(t0 + tt) * H4 + col] = acc[tt];
}

// ---------------- init h = h0, c = 0 ----------------
__global__ __launch_bounds__(256) void init_kernel(const float* __restrict__ h0,
                                                   float* __restrict__ h,
                                                   float* __restrict__ c) {
    int i = blockIdx.x * 256 + threadIdx.x;
    h[i] = h0[i];
    c[i] = 0.f;
}

// ---------------- split-K matvec: zpart[ks] = h[k-range] @ Mf[k-range] ----------------
__global__ __launch_bounds__(256) void matvec_kernel(const float* __restrict__ M,
                                                     const float* __restrict__ h,
                                                     float* __restrict__ zpart) {
    int col4 = blockIdx.x * 256 + threadIdx.x;   // float4 column index, [0, 4096)
    int k0   = blockIdx.y * KC;
    __shared__ float hs[KC];
    if (threadIdx.x < KC) hs[threadIdx.x] = h[k0 + threadIdx.x];
    __syncthreads();
    const float4* M4 = (const float4*)M;
    size_t base = (size_t)k0 * (H4 / 4) + col4;
    float4 acc; acc.x = acc.y = acc.z = acc.w = 0.f;
#pragma unroll 4
    for (int k = 0; k < KC; ++k) {
        float4 m = M4[base + (size_t)k * (H4 / 4)];
        float hk = hs[k];
        acc.x += hk * m.x; acc.y += hk * m.y; acc.z += hk * m.z; acc.w += hk * m.w;
    }
    ((float4*)zpart)[(size_t)blockIdx.y * (H4 / 4) + col4] = acc;
}

// fallback: read W[E:] and U separately (no fused matrix in ws)
__global__ __launch_bounds__(256) void matvec2_kernel(const float* __restrict__ Wh,
                                                      const float* __restrict__ U,
                                                      const float* __restrict__ h,
                                                      float* __restrict__ zpart) {
    int col4 = blockIdx.x * 256 + threadIdx.x;
    int k0   = blockIdx.y * KC;
    __shared__ float hs[KC];
    if (threadIdx.x < KC) hs[threadIdx.x] = h[k0 + threadIdx.x];
    __syncthreads();
    const float4* W4 = (const float4*)Wh;
    const float4* U4 = (const float4*)U;
    size_t base = (size_t)k0 * (H4 / 4) + col4;
    float4 acc; acc.x = acc.y = acc.z = acc.w = 0.f;
#pragma unroll 2
    for (int k = 0; k < KC; ++k) {
        size_t idx = base + (size_t)k * (H4 / 4);
        float4 w = W4[idx];
        float4 u = U4[idx];
        float hk = hs[k];
        acc.x += hk * (w.x + u.x); acc.y += hk * (w.y + u.y);
        acc.z += hk * (w.z + u.z); acc.w += hk * (w.w + u.w);
    }
    ((float4*)zpart)[(size_t)blockIdx.y * (H4 / 4) + col4] = acc;
}

// ---------------- reduce partials + LSTM gates + state update ----------------
__global__ __launch_bounds__(256) void gate_kernel(const float* __restrict__ zpart,
                                                   const float* __restrict__ X,
                                                   float* __restrict__ h,
                                                   float* __restrict__ c,
                                                   float* __restrict__ orders,
                                                   int t) {
    int j = blockIdx.x * 256 + threadIdx.x;   // [0, Hn)
    const float* Xt = X + (size_t)t * H4;
    float zi = Xt[j];
    float zf = Xt[j + Hn];
    float zg = Xt[j + 2 * Hn];
    float zo = Xt[j + 3 * Hn];
#pragma unroll 8
    for (int ks = 0; ks < KSPLIT; ++ks) {
        const float* zp = zpart + (size_t)ks * H4;
        zi += zp[j];
        zf += zp[j + Hn];
        zg += zp[j + 2 * Hn];
        zo += zp[j + 3 * Hn];
    }
    float gi = 1.f / (1.f + expf(-zi));
    float gf = 1.f / (1.f + expf(-zf));
    float go = 1.f / (1.f + expf(-zo));
    float cn = gf * c[j] + gi * zg;     // candidate activation = identity
    float ho = h[j];
    float hn = go * cn;                 // output activation = identity
    orders[(size_t)t * Hn + j] = ho;    // emit PRE-update h
    h[j] = hn;
    c[j] = cn;
}

extern "C" void kernel_launch(void* const* d_in, const int* in_sizes, int n_in,
                              void* d_out, int out_size, void* d_ws, size_t ws_size,
                              hipStream_t stream) {
    const float* henc = (const float*)d_in[0];
    const float* h0   = (const float*)d_in[1];
    const float* W    = (const float*)d_in[2];
    const float* U    = (const float*)d_in[3];
    const float* bias = (const float*)d_in[4];
    float* out = (float*)d_out;

    const size_t needM  = (size_t)Hn * H4 * sizeof(float);      // 268 MB
    const size_t needX  = (size_t)Pn * H4 * sizeof(float);      // 5.3 MB
    const size_t needZ  = (size_t)KSPLIT * H4 * sizeof(float);  // 4.2 MB
    const size_t needHC = (size_t)Hn * 2 * sizeof(float);

    char* ws = (char*)d_ws;
    bool fused = ws_size >= needM + needX + needZ + needHC;

    float *Mf, *X, *zpart, *h, *c;
    if (fused) {
        Mf    = (float*)ws;
        X     = (float*)(ws + needM);
        zpart = (float*)(ws + needM + needX);
        h     = (float*)(ws + needM + needX + needZ);
        c     = h + Hn;
    } else {
        Mf    = nullptr;
        X     = (float*)ws;
        zpart = (float*)(ws + needX);
        h     = (float*)(ws + needX + needZ);
        c     = h + Hn;
    }

    if (fused) {
        fuse_kernel<<<dim3((Hn * (H4 / 4)) / 256), 256, 0, stream>>>(W, U, Mf);
    }
    xproj_kernel<<<dim3(H4 / 256, (Pn + TT - 1) / TT), 256, 0, stream>>>(henc, W, bias, X);
    init_kernel<<<dim3(Hn / 256), 256, 0, stream>>>(h0, h, c);

    for (int t = 0; t < Pn; ++t) {
        if (fused) {
            matvec_kernel<<<dim3(H4 / 4 / 256, KSPLIT), 256, 0, stream>>>(Mf, h, zpart);
        } else {
            matvec2_kernel<<<dim3(H4 / 4 / 256, KSPLIT), 256, 0, stream>>>(
                W + (size_t)En * H4, U, h, zpart);
        }
        gate_kernel<<<dim3(Hn / 256), 256, 0, stream>>>(zpart, X, h, c, out, t);
    }
}

// Round 2
// 2537.686 us; speedup vs baseline: 2.0559x; 2.0559x over previous
//
#include <hip/hip_runtime.h>
#include <hip/hip_fp16.h>
#include <cstddef>

#define Pn 81
#define En 256
#define Hn 4096
#define H4 16384          // 4*Hn
#define KSPLIT 64
#define KC (Hn / KSPLIT)  // 64
#define TT 16             // t-tile for X projection

// ---------------- Mh = f16(W[E:,:] + U)   (Hn x H4) ----------------
__global__ __launch_bounds__(256) void fuse16_kernel(const float* __restrict__ W,
                                                     const float* __restrict__ U,
                                                     __half* __restrict__ Mh) {
    size_t i = (size_t)blockIdx.x * 256 + threadIdx.x;  // 8-element group index
    const float4* W4 = (const float4*)(W + (size_t)En * H4);
    const float4* U4 = (const float4*)U;
    float4 a0 = W4[2 * i], a1 = W4[2 * i + 1];
    float4 b0 = U4[2 * i], b1 = U4[2 * i + 1];
    alignas(16) __half tmp[8];
    tmp[0] = __float2half(a0.x + b0.x);
    tmp[1] = __float2half(a0.y + b0.y);
    tmp[2] = __float2half(a0.z + b0.z);
    tmp[3] = __float2half(a0.w + b0.w);
    tmp[4] = __float2half(a1.x + b1.x);
    tmp[5] = __float2half(a1.y + b1.y);
    tmp[6] = __float2half(a1.z + b1.z);
    tmp[7] = __float2half(a1.w + b1.w);
    ((uint4*)Mh)[i] = *(const uint4*)tmp;
}

// ---------------- X[t] = h_enc[t] @ W[:E] + b   (Pn x H4) ----------------
__global__ __launch_bounds__(256) void xproj_kernel(const float* __restrict__ henc,
                                                    const float* __restrict__ W,
                                                    const float* __restrict__ bias,
                                                    float* __restrict__ X) {
    int col = blockIdx.x * 256 + threadIdx.x;
    int t0  = blockIdx.y * TT;
    __shared__ float hs[TT][En];
    for (int r = threadIdx.x; r < TT * En; r += 256) {
        int tt = r >> 8;
        int e  = r & (En - 1);
        hs[tt][e] = (t0 + tt < Pn) ? henc[(size_t)(t0 + tt) * En + e] : 0.f;
    }
    __syncthreads();
    float acc[TT];
    float bc = bias[col];
#pragma unroll
    for (int tt = 0; tt < TT; ++tt) acc[tt] = bc;
    for (int e = 0; e < En; ++e) {
        float w = W[(size_t)e * H4 + col];
#pragma unroll
        for (int tt = 0; tt < TT; ++tt) acc[tt] += hs[tt][e] * w;
    }
    int nt = Pn - t0; if (nt > TT) nt = TT;
    for (int tt = 0; tt < nt; ++tt) X[(size_t)(t0 + tt) * H4 + col] = acc[tt];
}

// ---------------- init h = h0, c = 0 ----------------
__global__ __launch_bounds__(256) void init_kernel(const float* __restrict__ h0,
                                                   float* __restrict__ h,
                                                   float* __restrict__ c) {
    int i = blockIdx.x * 256 + threadIdx.x;
    h[i] = h0[i];
    c[i] = 0.f;
}

// ---------------- split-K matvec (fp16 M): zpart[ks] = h[k-range] @ Mh[k-range] ----------------
__global__ __launch_bounds__(256) void matvec16_kernel(const __half* __restrict__ M,
                                                       const float* __restrict__ h,
                                                       float* __restrict__ zpart) {
    int col8 = blockIdx.x * 256 + threadIdx.x;   // 8-half column group, [0, 2048)
    int k0   = blockIdx.y * KC;
    __shared__ float hs[KC];
    if (threadIdx.x < KC) hs[threadIdx.x] = h[k0 + threadIdx.x];
    __syncthreads();
    const uint4* M8 = (const uint4*)M;           // 8 halves per uint4
    const size_t rowstride = H4 / 8;
    size_t base = (size_t)k0 * rowstride + col8;
    float acc[8];
#pragma unroll
    for (int p = 0; p < 8; ++p) acc[p] = 0.f;
#pragma unroll 8
    for (int k = 0; k < KC; ++k) {
        uint4 raw = M8[base + (size_t)k * rowstride];
        float hk = hs[k];
        const __half2* hp = (const __half2*)&raw;
#pragma unroll
        for (int p = 0; p < 4; ++p) {
            float2 f = __half22float2(hp[p]);
            acc[2 * p]     += hk * f.x;
            acc[2 * p + 1] += hk * f.y;
        }
    }
    float4* zp = (float4*)(zpart + (size_t)blockIdx.y * H4 + (size_t)col8 * 8);
    zp[0] = make_float4(acc[0], acc[1], acc[2], acc[3]);
    zp[1] = make_float4(acc[4], acc[5], acc[6], acc[7]);
}

// fallback: f32 W[E:] + U read separately (ws too small for fused fp16 matrix)
__global__ __launch_bounds__(256) void matvec2_kernel(const float* __restrict__ Wh,
                                                      const float* __restrict__ U,
                                                      const float* __restrict__ h,
                                                      float* __restrict__ zpart) {
    int col4 = blockIdx.x * 256 + threadIdx.x;
    int k0   = blockIdx.y * KC;
    __shared__ float hs[KC];
    if (threadIdx.x < KC) hs[threadIdx.x] = h[k0 + threadIdx.x];
    __syncthreads();
    const float4* W4 = (const float4*)Wh;
    const float4* U4 = (const float4*)U;
    size_t base = (size_t)k0 * (H4 / 4) + col4;
    float4 acc; acc.x = acc.y = acc.z = acc.w = 0.f;
#pragma unroll 2
    for (int k = 0; k < KC; ++k) {
        size_t idx = base + (size_t)k * (H4 / 4);
        float4 w = W4[idx];
        float4 u = U4[idx];
        float hk = hs[k];
        acc.x += hk * (w.x + u.x); acc.y += hk * (w.y + u.y);
        acc.z += hk * (w.z + u.z); acc.w += hk * (w.w + u.w);
    }
    ((float4*)zpart)[(size_t)blockIdx.y * (H4 / 4) + col4] = acc;
}

// ---------------- reduce partials + LSTM gates + state update ----------------
// 64 blocks x 256 threads; each block owns 64 j's; 4 thread-groups split the ks-reduction.
__global__ __launch_bounds__(256) void gate_kernel(const float* __restrict__ zpart,
                                                   const float* __restrict__ X,
                                                   float* __restrict__ h,
                                                   float* __restrict__ c,
                                                   float* __restrict__ orders,
                                                   int t) {
    int lane = threadIdx.x & 63;
    int g    = threadIdx.x >> 6;          // 0..3
    int j    = blockIdx.x * 64 + lane;    // [0, Hn)
    float s0 = 0.f, s1 = 0.f, s2 = 0.f, s3 = 0.f;
    for (int ks = g; ks < KSPLIT; ks += 4) {
        const float* zp = zpart + (size_t)ks * H4;
        s0 += zp[j];
        s1 += zp[j + Hn];
        s2 += zp[j + 2 * Hn];
        s3 += zp[j + 3 * Hn];
    }
    __shared__ float red[4][4][64];       // [gate][group][lane]
    red[0][g][lane] = s0;
    red[1][g][lane] = s1;
    red[2][g][lane] = s2;
    red[3][g][lane] = s3;
    __syncthreads();
    if (g == 0) {
        const float* Xt = X + (size_t)t * H4;
        float zi = Xt[j]          + red[0][0][lane] + red[0][1][lane] + red[0][2][lane] + red[0][3][lane];
        float zf = Xt[j + Hn]     + red[1][0][lane] + red[1][1][lane] + red[1][2][lane] + red[1][3][lane];
        float zg = Xt[j + 2 * Hn] + red[2][0][lane] + red[2][1][lane] + red[2][2][lane] + red[2][3][lane];
        float zo = Xt[j + 3 * Hn] + red[3][0][lane] + red[3][1][lane] + red[3][2][lane] + red[3][3][lane];
        float gi = 1.f / (1.f + __expf(-zi));
        float gf = 1.f / (1.f + __expf(-zf));
        float go = 1.f / (1.f + __expf(-zo));
        float cn = gf * c[j] + gi * zg;     // candidate activation = identity
        float ho = h[j];
        float hn = go * cn;                 // output activation = identity
        orders[(size_t)t * Hn + j] = ho;    // emit PRE-update h
        h[j] = hn;
        c[j] = cn;
    }
}

extern "C" void kernel_launch(void* const* d_in, const int* in_sizes, int n_in,
                              void* d_out, int out_size, void* d_ws, size_t ws_size,
                              hipStream_t stream) {
    const float* henc = (const float*)d_in[0];
    const float* h0   = (const float*)d_in[1];
    const float* W    = (const float*)d_in[2];
    const float* U    = (const float*)d_in[3];
    const float* bias = (const float*)d_in[4];
    float* out = (float*)d_out;

    const size_t needM  = (size_t)Hn * H4 * sizeof(__half);    // 134 MB fp16
    const size_t needX  = (size_t)Pn * H4 * sizeof(float);     // 5.3 MB
    const size_t needZ  = (size_t)KSPLIT * H4 * sizeof(float); // 4.2 MB
    const size_t needHC = (size_t)Hn * 2 * sizeof(float);

    char* ws = (char*)d_ws;
    bool fused = ws_size >= needM + needX + needZ + needHC;

    __half* Mh;
    float *X, *zpart, *h, *c;
    if (fused) {
        Mh    = (__half*)ws;
        X     = (float*)(ws + needM);
        zpart = (float*)(ws + needM + needX);
        h     = (float*)(ws + needM + needX + needZ);
        c     = h + Hn;
    } else {
        Mh    = nullptr;
        X     = (float*)ws;
        zpart = (float*)(ws + needX);
        h     = (float*)(ws + needX + needZ);
        c     = h + Hn;
    }

    if (fused) {
        fuse16_kernel<<<dim3(((size_t)Hn * H4 / 8) / 256), 256, 0, stream>>>(W, U, Mh);
    }
    xproj_kernel<<<dim3(H4 / 256, (Pn + TT - 1) / TT), 256, 0, stream>>>(henc, W, bias, X);
    init_kernel<<<dim3(Hn / 256), 256, 0, stream>>>(h0, h, c);

    for (int t = 0; t < Pn; ++t) {
        if (fused) {
            matvec16_kernel<<<dim3(H4 / 8 / 256, KSPLIT), 256, 0, stream>>>(Mh, h, zpart);
        } else {
            matvec2_kernel<<<dim3(H4 / 4 / 256, KSPLIT), 256, 0, stream>>>(
                W + (size_t)En * H4, U, h, zpart);
        }
        gate_kernel<<<dim3(Hn / 64), 256, 0, stream>>>(zpart, X, h, c, out, t);
    }
}

// Round 4
// 2496.293 us; speedup vs baseline: 2.0899x; 1.0166x over previous
//
#include <hip/hip_runtime.h>
#include <hip/hip_fp16.h>
#include <cstddef>

#define Pn 81
#define En 256
#define Hn 4096
#define H4 16384          // 4*Hn
#define KSPLIT 64
#define KC (Hn / KSPLIT)  // 64
#define CG 8              // column groups: 8 blocks x 2048 cols
#define TT 16             // t-tile for X projection

typedef float  fx4 __attribute__((ext_vector_type(4)));
typedef unsigned int ux4 __attribute__((ext_vector_type(4)));

// ---------------- Mh = f16(W[E:,:] + U)   (Hn x H4), NT streams ----------------
__global__ __launch_bounds__(256) void fuse16_kernel(const float* __restrict__ W,
                                                     const float* __restrict__ U,
                                                     __half* __restrict__ Mh) {
    size_t i = (size_t)blockIdx.x * 256 + threadIdx.x;  // 16-element group index
    const fx4* W4 = (const fx4*)(W + (size_t)En * H4);
    const fx4* U4 = (const fx4*)U;
#pragma unroll
    for (int p = 0; p < 2; ++p) {
        size_t g = 4 * i + 2 * p;
        fx4 a0 = __builtin_nontemporal_load(&W4[g]);
        fx4 a1 = __builtin_nontemporal_load(&W4[g + 1]);
        fx4 b0 = __builtin_nontemporal_load(&U4[g]);
        fx4 b1 = __builtin_nontemporal_load(&U4[g + 1]);
        alignas(16) __half tmp[8];
        tmp[0] = __float2half(a0.x + b0.x);
        tmp[1] = __float2half(a0.y + b0.y);
        tmp[2] = __float2half(a0.z + b0.z);
        tmp[3] = __float2half(a0.w + b0.w);
        tmp[4] = __float2half(a1.x + b1.x);
        tmp[5] = __float2half(a1.y + b1.y);
        tmp[6] = __float2half(a1.z + b1.z);
        tmp[7] = __float2half(a1.w + b1.w);
        __builtin_nontemporal_store(*(const ux4*)tmp, &((ux4*)Mh)[2 * i + p]);
    }
}

// ---------------- X[t] = h_enc[t] @ W[:E] + b   (Pn x H4) ----------------
__global__ __launch_bounds__(256) void xproj_kernel(const float* __restrict__ henc,
                                                    const float* __restrict__ W,
                                                    const float* __restrict__ bias,
                                                    float* __restrict__ X) {
    int col = blockIdx.x * 256 + threadIdx.x;
    int t0  = blockIdx.y * TT;
    __shared__ float hs[TT][En];
    for (int r = threadIdx.x; r < TT * En; r += 256) {
        int tt = r >> 8;
        int e  = r & (En - 1);
        hs[tt][e] = (t0 + tt < Pn) ? henc[(size_t)(t0 + tt) * En + e] : 0.f;
    }
    __syncthreads();
    float acc[TT];
    float bc = bias[col];
#pragma unroll
    for (int tt = 0; tt < TT; ++tt) acc[tt] = bc;
    for (int e = 0; e < En; ++e) {
        float w = W[(size_t)e * H4 + col];
#pragma unroll
        for (int tt = 0; tt < TT; ++tt) acc[tt] += hs[tt][e] * w;
    }
    int nt = Pn - t0; if (nt > TT) nt = TT;
    for (int tt = 0; tt < nt; ++tt) X[(size_t)(t0 + tt) * H4 + col] = acc[tt];
}

// ---------------- init: orders[0] = h0, c0 = 0 ----------------
__global__ __launch_bounds__(256) void init_kernel(const float* __restrict__ h0,
                                                   float* __restrict__ orders,
                                                   float* __restrict__ c0) {
    int i = blockIdx.x * 256 + threadIdx.x;
    orders[i] = h0[i];
    c0[i] = 0.f;
}

// ---------------- fused step: gate (h_t from zprev) + matvec (zcur = h_t @ Mh chunk) -----
// grid (CG=8, KSPLIT=64), 256 threads. Block (cg,kc) gate-computes h_t[kc*64 .. +64)
// (redundant across cg — identical values, disjoint-from-read buffers so no RMW race),
// keeps them in LDS, then streams its 64x2048 fp16 slice of Mh.
__global__ __launch_bounds__(256) void step_kernel(const __half* __restrict__ M,
                                                   const float* __restrict__ X,
                                                   const float* __restrict__ zprev,
                                                   float* __restrict__ zcur,
                                                   const float* __restrict__ cprev,
                                                   float* __restrict__ ccur,
                                                   float* __restrict__ orders,
                                                   const float* __restrict__ h0,
                                                   int t) {
    const int cg  = blockIdx.x;          // 0..CG-1
    const int kc  = blockIdx.y;          // 0..KSPLIT-1
    const int tid = threadIdx.x;
    __shared__ float hs[KC];

    if (t == 0) {
        if (tid < KC) hs[tid] = h0[kc * KC + tid];
    } else {
        const int lane = tid & 63;
        const int g    = tid >> 6;       // 0..3
        const int j    = kc * KC + lane;
        float s0 = 0.f, s1 = 0.f, s2 = 0.f, s3 = 0.f;
        for (int ks = g; ks < KSPLIT; ks += 4) {
            const float* zp = zprev + (size_t)ks * H4;
            s0 += zp[j];
            s1 += zp[j + Hn];
            s2 += zp[j + 2 * Hn];
            s3 += zp[j + 3 * Hn];
        }
        __shared__ float red[4][4][64];
        red[0][g][lane] = s0;
        red[1][g][lane] = s1;
        red[2][g][lane] = s2;
        red[3][g][lane] = s3;
        __syncthreads();
        if (g == 0) {
            const float* Xt = X + (size_t)(t - 1) * H4;
            float zi = Xt[j]          + red[0][0][lane] + red[0][1][lane] + red[0][2][lane] + red[0][3][lane];
            float zf = Xt[j + Hn]     + red[1][0][lane] + red[1][1][lane] + red[1][2][lane] + red[1][3][lane];
            float zg = Xt[j + 2 * Hn] + red[2][0][lane] + red[2][1][lane] + red[2][2][lane] + red[2][3][lane];
            float zo = Xt[j + 3 * Hn] + red[3][0][lane] + red[3][1][lane] + red[3][2][lane] + red[3][3][lane];
            float gi = 1.f / (1.f + __expf(-zi));
            float gf = 1.f / (1.f + __expf(-zf));
            float go = 1.f / (1.f + __expf(-zo));
            float cn = gf * cprev[j] + gi * zg;   // candidate activation = identity
            float hn = go * cn;                   // output activation = identity
            orders[(size_t)t * Hn + j] = hn;      // orders[t] = h_t
            ccur[j] = cn;
            hs[lane] = hn;
        }
    }
    __syncthreads();

    // ---- matvec: zcur[kc][cols] = sum_k hs[k] * M[kc*KC+k][cols] ----
    const int col8 = cg * 256 + tid;             // 8-half column group, [0, 2048)
    const ux4* M8 = (const ux4*)M;
    const size_t rowstride = H4 / 8;             // 2048
    size_t base = (size_t)(kc * KC) * rowstride + col8;
    float acc[8];
#pragma unroll
    for (int p = 0; p < 8; ++p) acc[p] = 0.f;
#pragma unroll 8
    for (int k = 0; k < KC; ++k) {
        ux4 raw = M8[base + (size_t)k * rowstride];
        float hk = hs[k];
        const __half2* hp = (const __half2*)&raw;
#pragma unroll
        for (int p = 0; p < 4; ++p) {
            float2 f = __half22float2(hp[p]);
            acc[2 * p]     += hk * f.x;
            acc[2 * p + 1] += hk * f.y;
        }
    }
    float4* zp = (float4*)(zcur + (size_t)kc * H4 + (size_t)col8 * 8);
    zp[0] = make_float4(acc[0], acc[1], acc[2], acc[3]);
    zp[1] = make_float4(acc[4], acc[5], acc[6], acc[7]);
}

// ---------------- epilogue: orders[80] = h_80 (gate only, no matvec) ----------------
__global__ __launch_bounds__(256) void final_gate_kernel(const float* __restrict__ zprev,
                                                         const float* __restrict__ X,
                                                         const float* __restrict__ cprev,
                                                         float* __restrict__ orders) {
    const int lane = threadIdx.x & 63;
    const int g    = threadIdx.x >> 6;
    const int j    = blockIdx.x * 64 + lane;
    float s0 = 0.f, s1 = 0.f, s2 = 0.f, s3 = 0.f;
    for (int ks = g; ks < KSPLIT; ks += 4) {
        const float* zp = zprev + (size_t)ks * H4;
        s0 += zp[j];
        s1 += zp[j + Hn];
        s2 += zp[j + 2 * Hn];
        s3 += zp[j + 3 * Hn];
    }
    __shared__ float red[4][4][64];
    red[0][g][lane] = s0;
    red[1][g][lane] = s1;
    red[2][g][lane] = s2;
    red[3][g][lane] = s3;
    __syncthreads();
    if (g == 0) {
        const float* Xt = X + (size_t)(Pn - 2) * H4;   // X[79]
        float zi = Xt[j]          + red[0][0][lane] + red[0][1][lane] + red[0][2][lane] + red[0][3][lane];
        float zf = Xt[j + Hn]     + red[1][0][lane] + red[1][1][lane] + red[1][2][lane] + red[1][3][lane];
        float zg = Xt[j + 2 * Hn] + red[2][0][lane] + red[2][1][lane] + red[2][2][lane] + red[2][3][lane];
        float zo = Xt[j + 3 * Hn] + red[3][0][lane] + red[3][1][lane] + red[3][2][lane] + red[3][3][lane];
        float gi = 1.f / (1.f + __expf(-zi));
        float gf = 1.f / (1.f + __expf(-zf));
        float go = 1.f / (1.f + __expf(-zo));
        float cn = gf * cprev[j] + gi * zg;
        orders[(size_t)(Pn - 1) * Hn + j] = go * cn;
    }
}

// ================= fallback path (ws too small): f32, separate kernels =================
__global__ __launch_bounds__(256) void fb_init_kernel(const float* __restrict__ h0,
                                                      float* __restrict__ h,
                                                      float* __restrict__ c) {
    int i = blockIdx.x * 256 + threadIdx.x;
    h[i] = h0[i];
    c[i] = 0.f;
}

__global__ __launch_bounds__(256) void matvec2_kernel(const float* __restrict__ Wh,
                                                      const float* __restrict__ U,
                                                      const float* __restrict__ h,
                                                      float* __restrict__ zpart) {
    int col4 = blockIdx.x * 256 + threadIdx.x;
    int k0   = blockIdx.y * KC;
    __shared__ float hs[KC];
    if (threadIdx.x < KC) hs[threadIdx.x] = h[k0 + threadIdx.x];
    __syncthreads();
    const float4* W4 = (const float4*)Wh;
    const float4* U4 = (const float4*)U;
    size_t base = (size_t)k0 * (H4 / 4) + col4;
    float4 acc; acc.x = acc.y = acc.z = acc.w = 0.f;
#pragma unroll 2
    for (int k = 0; k < KC; ++k) {
        size_t idx = base + (size_t)k * (H4 / 4);
        float4 w = W4[idx];
        float4 u = U4[idx];
        float hk = hs[k];
        acc.x += hk * (w.x + u.x); acc.y += hk * (w.y + u.y);
        acc.z += hk * (w.z + u.z); acc.w += hk * (w.w + u.w);
    }
    ((float4*)zpart)[(size_t)blockIdx.y * (H4 / 4) + col4] = acc;
}

__global__ __launch_bounds__(256) void gate_kernel(const float* __restrict__ zpart,
                                                   const float* __restrict__ X,
                                                   float* __restrict__ h,
                                                   float* __restrict__ c,
                                                   float* __restrict__ orders,
                                                   int t) {
    int lane = threadIdx.x & 63;
    int g    = threadIdx.x >> 6;
    int j    = blockIdx.x * 64 + lane;
    float s0 = 0.f, s1 = 0.f, s2 = 0.f, s3 = 0.f;
    for (int ks = g; ks < KSPLIT; ks += 4) {
        const float* zp = zpart + (size_t)ks * H4;
        s0 += zp[j];
        s1 += zp[j + Hn];
        s2 += zp[j + 2 * Hn];
        s3 += zp[j + 3 * Hn];
    }
    __shared__ float red[4][4][64];
    red[0][g][lane] = s0;
    red[1][g][lane] = s1;
    red[2][g][lane] = s2;
    red[3][g][lane] = s3;
    __syncthreads();
    if (g == 0) {
        const float* Xt = X + (size_t)t * H4;
        float zi = Xt[j]          + red[0][0][lane] + red[0][1][lane] + red[0][2][lane] + red[0][3][lane];
        float zf = Xt[j + Hn]     + red[1][0][lane] + red[1][1][lane] + red[1][2][lane] + red[1][3][lane];
        float zg = Xt[j + 2 * Hn] + red[2][0][lane] + red[2][1][lane] + red[2][2][lane] + red[2][3][lane];
        float zo = Xt[j + 3 * Hn] + red[3][0][lane] + red[3][1][lane] + red[3][2][lane] + red[3][3][lane];
        float gi = 1.f / (1.f + __expf(-zi));
        float gf = 1.f / (1.f + __expf(-zf));
        float go = 1.f / (1.f + __expf(-zo));
        float cn = gf * c[j] + gi * zg;
        float ho = h[j];
        float hn = go * cn;
        orders[(size_t)t * Hn + j] = ho;
        h[j] = hn;
        c[j] = cn;
    }
}

extern "C" void kernel_launch(void* const* d_in, const int* in_sizes, int n_in,
                              void* d_out, int out_size, void* d_ws, size_t ws_size,
                              hipStream_t stream) {
    const float* henc = (const float*)d_in[0];
    const float* h0   = (const float*)d_in[1];
    const float* W    = (const float*)d_in[2];
    const float* U    = (const float*)d_in[3];
    const float* bias = (const float*)d_in[4];
    float* out = (float*)d_out;

    const size_t needM = (size_t)Hn * H4 * sizeof(__half);    // 134 MB fp16
    const size_t needX = (size_t)Pn * H4 * sizeof(float);     // 5.3 MB
    const size_t needZ = (size_t)KSPLIT * H4 * sizeof(float); // 4.2 MB (x2)
    const size_t needC = (size_t)Hn * sizeof(float);          // 16 KB (x2)

    char* ws = (char*)d_ws;
    const bool fused = ws_size >= needM + needX + 2 * needZ + 2 * needC;

    if (fused) {
        __half* Mh = (__half*)ws;
        float*  X  = (float*)(ws + needM);
        float*  zp[2];
        zp[0] = (float*)(ws + needM + needX);
        zp[1] = (float*)(ws + needM + needX + needZ);
        float* cb[2];
        cb[0] = (float*)(ws + needM + needX + 2 * needZ);
        cb[1] = cb[0] + Hn;

        fuse16_kernel<<<dim3(((size_t)Hn * H4 / 16) / 256), 256, 0, stream>>>(W, U, Mh);
        xproj_kernel<<<dim3(H4 / 256, (Pn + TT - 1) / TT), 256, 0, stream>>>(henc, W, bias, X);
        init_kernel<<<dim3(Hn / 256), 256, 0, stream>>>(h0, out, cb[0]);

        for (int t = 0; t < Pn - 1; ++t) {   // 80 fused steps (z_80 is never needed)
            step_kernel<<<dim3(CG, KSPLIT), 256, 0, stream>>>(
                Mh, X, zp[(t + 1) & 1], zp[t & 1],
                cb[(t + 1) & 1], cb[t & 1], out, h0, t);
        }
        // orders[80] from zpart of t=79 (in zp[79&1]=zp[1]) and c_79 (in cb[1])
        final_gate_kernel<<<dim3(Hn / 64), 256, 0, stream>>>(zp[1], X, cb[1], out);
    } else {
        float* X     = (float*)ws;
        float* zpart = (float*)(ws + needX);
        float* h     = (float*)(ws + needX + needZ);
        float* c     = h + Hn;

        xproj_kernel<<<dim3(H4 / 256, (Pn + TT - 1) / TT), 256, 0, stream>>>(henc, W, bias, X);
        fb_init_kernel<<<dim3(Hn / 256), 256, 0, stream>>>(h0, h, c);
        for (int t = 0; t < Pn; ++t) {
            matvec2_kernel<<<dim3(H4 / 4 / 256, KSPLIT), 256, 0, stream>>>(
                W + (size_t)En * H4, U, h, zpart);
            gate_kernel<<<dim3(Hn / 64), 256, 0, stream>>>(zpart, X, h, c, out, t);
        }
    }
}

// Round 5
// 2318.256 us; speedup vs baseline: 2.2505x; 1.0768x over previous
//
#include <hip/hip_runtime.h>
#include <hip/hip_fp16.h>
#include <cstddef>

#define Pn 81
#define En 256
#define Hn 4096
#define H4 16384          // 4*Hn
#define KSPLIT 64
#define KC (Hn / KSPLIT)  // 64
#define CG 8              // column groups: 8 blocks x 2048 cols
#define TT 16             // t-tile for X projection

// ---------------- X[t] = h_enc[t] @ W[:E] + b   (Pn x H4) ----------------
__global__ __launch_bounds__(256) void xproj_kernel(const float* __restrict__ henc,
                                                    const float* __restrict__ W,
                                                    const float* __restrict__ bias,
                                                    float* __restrict__ X) {
    int col = blockIdx.x * 256 + threadIdx.x;
    int t0  = blockIdx.y * TT;
    __shared__ float hs[TT][En];
    for (int r = threadIdx.x; r < TT * En; r += 256) {
        int tt = r >> 8;
        int e  = r & (En - 1);
        hs[tt][e] = (t0 + tt < Pn) ? henc[(size_t)(t0 + tt) * En + e] : 0.f;
    }
    __syncthreads();
    float acc[TT];
    float bc = bias[col];
#pragma unroll
    for (int tt = 0; tt < TT; ++tt) acc[tt] = bc;
    for (int e = 0; e < En; ++e) {
        float w = W[(size_t)e * H4 + col];
#pragma unroll
        for (int tt = 0; tt < TT; ++tt) acc[tt] += hs[tt][e] * w;
    }
    int nt = Pn - t0; if (nt > TT) nt = TT;
    for (int tt = 0; tt < nt; ++tt) X[(size_t)(t0 + tt) * H4 + col] = acc[tt];
}

// ---------------- init: orders[0] = h0, c0 = 0 ----------------
__global__ __launch_bounds__(256) void init_kernel(const float* __restrict__ h0,
                                                   float* __restrict__ orders,
                                                   float* __restrict__ c0) {
    int i = blockIdx.x * 256 + threadIdx.x;
    orders[i] = h0[i];
    c0[i] = 0.f;
}

// ------------- step 0 fused with weight prep: Mh = f16(W[E:]+U); z0 = h0 @ Mf -------------
// grid (CG, KSPLIT), 512 threads. Block (cg,kc): rows kc*64..+64 (two 32-row halves),
// f32 cols cg*2048..+2048. Reads W/U once, emits fp16 Mh and z0 partials.
__global__ __launch_bounds__(512) void fuse_step0_kernel(const float* __restrict__ W,
                                                         const float* __restrict__ U,
                                                         const float* __restrict__ h0,
                                                         __half* __restrict__ Mh,
                                                         float* __restrict__ zcur) {
    const int cg  = blockIdx.x;
    const int kc  = blockIdx.y;
    const int tid = threadIdx.x;
    __shared__ float hs[KC];
    if (tid < KC) hs[tid] = h0[kc * KC + tid];
    __syncthreads();

    const int half = tid >> 8;        // 0 or 1
    const int t256 = tid & 255;
    const int c0   = cg * 2048 + t256 * 8;   // f32 column base (8 per thread)

    float acc[8];
#pragma unroll
    for (int p = 0; p < 8; ++p) acc[p] = 0.f;

#pragma unroll 4
    for (int k = 0; k < 32; ++k) {
        const int krow = kc * KC + half * 32 + k;
        const float4* Wp = (const float4*)(W + (size_t)(En + krow) * H4 + c0);
        const float4* Up = (const float4*)(U + (size_t)krow * H4 + c0);
        float4 w0 = Wp[0], w1 = Wp[1];
        float4 u0 = Up[0], u1 = Up[1];
        float m[8];
        m[0] = w0.x + u0.x; m[1] = w0.y + u0.y; m[2] = w0.z + u0.z; m[3] = w0.w + u0.w;
        m[4] = w1.x + u1.x; m[5] = w1.y + u1.y; m[6] = w1.z + u1.z; m[7] = w1.w + u1.w;
        alignas(16) __half hm[8];
#pragma unroll
        for (int p = 0; p < 8; ++p) hm[p] = __float2half(m[p]);
        *(uint4*)(Mh + (size_t)krow * H4 + c0) = *(const uint4*)hm;
        float hk = hs[half * 32 + k];
#pragma unroll
        for (int p = 0; p < 8; ++p) acc[p] += hk * m[p];
    }

    __shared__ float accbuf[256][8];
    if (half == 1) {
#pragma unroll
        for (int p = 0; p < 8; ++p) accbuf[t256][p] = acc[p];
    }
    __syncthreads();
    if (half == 0) {
#pragma unroll
        for (int p = 0; p < 8; ++p) acc[p] += accbuf[t256][p];
        float4* zp = (float4*)(zcur + (size_t)kc * H4 + (size_t)c0);
        zp[0] = make_float4(acc[0], acc[1], acc[2], acc[3]);
        zp[1] = make_float4(acc[4], acc[5], acc[6], acc[7]);
    }
}

// ---------------- fused step t>=1: gate (h_t from zprev) + matvec (zcur = h_t @ Mh) -----
// grid (CG, KSPLIT), 512 threads (16 waves/CU). Gate: 8 groups x 64 lanes split the
// ks-reduction. Matvec: two 256-thread halves split the 64-row k-range, LDS merge.
__global__ __launch_bounds__(512) void step_kernel(const __half* __restrict__ M,
                                                   const float* __restrict__ X,
                                                   const float* __restrict__ zprev,
                                                   float* __restrict__ zcur,
                                                   const float* __restrict__ cprev,
                                                   float* __restrict__ ccur,
                                                   float* __restrict__ orders,
                                                   int t) {
    const int cg  = blockIdx.x;
    const int kc  = blockIdx.y;
    const int tid = threadIdx.x;
    __shared__ float hs[KC];

    {
        const int lane = tid & 63;
        const int g    = tid >> 6;       // 0..7
        const int j    = kc * KC + lane;
        float s0 = 0.f, s1 = 0.f, s2 = 0.f, s3 = 0.f;
        for (int ks = g; ks < KSPLIT; ks += 8) {
            const float* zp = zprev + (size_t)ks * H4;
            s0 += zp[j];
            s1 += zp[j + Hn];
            s2 += zp[j + 2 * Hn];
            s3 += zp[j + 3 * Hn];
        }
        __shared__ float red[4][8][64];
        red[0][g][lane] = s0;
        red[1][g][lane] = s1;
        red[2][g][lane] = s2;
        red[3][g][lane] = s3;
        __syncthreads();
        if (g == 0) {
            const float* Xt = X + (size_t)(t - 1) * H4;
            float zi = Xt[j], zf = Xt[j + Hn], zg = Xt[j + 2 * Hn], zo = Xt[j + 3 * Hn];
#pragma unroll
            for (int g2 = 0; g2 < 8; ++g2) {
                zi += red[0][g2][lane];
                zf += red[1][g2][lane];
                zg += red[2][g2][lane];
                zo += red[3][g2][lane];
            }
            float gi = 1.f / (1.f + __expf(-zi));
            float gf = 1.f / (1.f + __expf(-zf));
            float go = 1.f / (1.f + __expf(-zo));
            float cn = gf * cprev[j] + gi * zg;   // candidate activation = identity
            float hn = go * cn;                   // output activation = identity
            orders[(size_t)t * Hn + j] = hn;      // orders[t] = h_t
            ccur[j] = cn;
            hs[lane] = hn;
        }
    }
    __syncthreads();

    // ---- matvec: zcur[kc][cols] = sum_k hs[k] * M[kc*KC+k][cols] ----
    const int half = tid >> 8;                   // 0 or 1
    const int t256 = tid & 255;
    const int col8 = cg * 256 + t256;            // 8-half column group, [0, 2048)
    const uint4* M8 = (const uint4*)M;
    const size_t rowstride = H4 / 8;             // 2048
    size_t base = (size_t)(kc * KC + half * 32) * rowstride + col8;
    float acc[8];
#pragma unroll
    for (int p = 0; p < 8; ++p) acc[p] = 0.f;
#pragma unroll 8
    for (int k = 0; k < 32; ++k) {
        uint4 raw = M8[base + (size_t)k * rowstride];
        float hk = hs[half * 32 + k];
        const __half2* hp = (const __half2*)&raw;
#pragma unroll
        for (int p = 0; p < 4; ++p) {
            float2 f = __half22float2(hp[p]);
            acc[2 * p]     += hk * f.x;
            acc[2 * p + 1] += hk * f.y;
        }
    }
    __shared__ float accbuf[256][8];
    if (half == 1) {
#pragma unroll
        for (int p = 0; p < 8; ++p) accbuf[t256][p] = acc[p];
    }
    __syncthreads();
    if (half == 0) {
#pragma unroll
        for (int p = 0; p < 8; ++p) acc[p] += accbuf[t256][p];
        float4* zp = (float4*)(zcur + (size_t)kc * H4 + (size_t)col8 * 8);
        zp[0] = make_float4(acc[0], acc[1], acc[2], acc[3]);
        zp[1] = make_float4(acc[4], acc[5], acc[6], acc[7]);
    }
}

// ---------------- epilogue: orders[80] = h_80 (gate only, no matvec) ----------------
__global__ __launch_bounds__(256) void final_gate_kernel(const float* __restrict__ zprev,
                                                         const float* __restrict__ X,
                                                         const float* __restrict__ cprev,
                                                         float* __restrict__ orders) {
    const int lane = threadIdx.x & 63;
    const int g    = threadIdx.x >> 6;
    const int j    = blockIdx.x * 64 + lane;
    float s0 = 0.f, s1 = 0.f, s2 = 0.f, s3 = 0.f;
    for (int ks = g; ks < KSPLIT; ks += 4) {
        const float* zp = zprev + (size_t)ks * H4;
        s0 += zp[j];
        s1 += zp[j + Hn];
        s2 += zp[j + 2 * Hn];
        s3 += zp[j + 3 * Hn];
    }
    __shared__ float red[4][4][64];
    red[0][g][lane] = s0;
    red[1][g][lane] = s1;
    red[2][g][lane] = s2;
    red[3][g][lane] = s3;
    __syncthreads();
    if (g == 0) {
        const float* Xt = X + (size_t)(Pn - 2) * H4;   // X[79]
        float zi = Xt[j]          + red[0][0][lane] + red[0][1][lane] + red[0][2][lane] + red[0][3][lane];
        float zf = Xt[j + Hn]     + red[1][0][lane] + red[1][1][lane] + red[1][2][lane] + red[1][3][lane];
        float zg = Xt[j + 2 * Hn] + red[2][0][lane] + red[2][1][lane] + red[2][2][lane] + red[2][3][lane];
        float zo = Xt[j + 3 * Hn] + red[3][0][lane] + red[3][1][lane] + red[3][2][lane] + red[3][3][lane];
        float gi = 1.f / (1.f + __expf(-zi));
        float gf = 1.f / (1.f + __expf(-zf));
        float go = 1.f / (1.f + __expf(-zo));
        float cn = gf * cprev[j] + gi * zg;
        orders[(size_t)(Pn - 1) * Hn + j] = go * cn;
    }
}

// ================= fallback path (ws too small): f32, separate kernels =================
__global__ __launch_bounds__(256) void fb_init_kernel(const float* __restrict__ h0,
                                                      float* __restrict__ h,
                                                      float* __restrict__ c) {
    int i = blockIdx.x * 256 + threadIdx.x;
    h[i] = h0[i];
    c[i] = 0.f;
}

__global__ __launch_bounds__(256) void matvec2_kernel(const float* __restrict__ Wh,
                                                      const float* __restrict__ U,
                                                      const float* __restrict__ h,
                                                      float* __restrict__ zpart) {
    int col4 = blockIdx.x * 256 + threadIdx.x;
    int k0   = blockIdx.y * KC;
    __shared__ float hs[KC];
    if (threadIdx.x < KC) hs[threadIdx.x] = h[k0 + threadIdx.x];
    __syncthreads();
    const float4* W4 = (const float4*)Wh;
    const float4* U4 = (const float4*)U;
    size_t base = (size_t)k0 * (H4 / 4) + col4;
    float4 acc; acc.x = acc.y = acc.z = acc.w = 0.f;
#pragma unroll 2
    for (int k = 0; k < KC; ++k) {
        size_t idx = base + (size_t)k * (H4 / 4);
        float4 w = W4[idx];
        float4 u = U4[idx];
        float hk = hs[k];
        acc.x += hk * (w.x + u.x); acc.y += hk * (w.y + u.y);
        acc.z += hk * (w.z + u.z); acc.w += hk * (w.w + u.w);
    }
    ((float4*)zpart)[(size_t)blockIdx.y * (H4 / 4) + col4] = acc;
}

__global__ __launch_bounds__(256) void gate_kernel(const float* __restrict__ zpart,
                                                   const float* __restrict__ X,
                                                   float* __restrict__ h,
                                                   float* __restrict__ c,
                                                   float* __restrict__ orders,
                                                   int t) {
    int lane = threadIdx.x & 63;
    int g    = threadIdx.x >> 6;
    int j    = blockIdx.x * 64 + lane;
    float s0 = 0.f, s1 = 0.f, s2 = 0.f, s3 = 0.f;
    for (int ks = g; ks < KSPLIT; ks += 4) {
        const float* zp = zpart + (size_t)ks * H4;
        s0 += zp[j];
        s1 += zp[j + Hn];
        s2 += zp[j + 2 * Hn];
        s3 += zp[j + 3 * Hn];
    }
    __shared__ float red[4][4][64];
    red[0][g][lane] = s0;
    red[1][g][lane] = s1;
    red[2][g][lane] = s2;
    red[3][g][lane] = s3;
    __syncthreads();
    if (g == 0) {
        const float* Xt = X + (size_t)t * H4;
        float zi = Xt[j]          + red[0][0][lane] + red[0][1][lane] + red[0][2][lane] + red[0][3][lane];
        float zf = Xt[j + Hn]     + red[1][0][lane] + red[1][1][lane] + red[1][2][lane] + red[1][3][lane];
        float zg = Xt[j + 2 * Hn] + red[2][0][lane] + red[2][1][lane] + red[2][2][lane] + red[2][3][lane];
        float zo = Xt[j + 3 * Hn] + red[3][0][lane] + red[3][1][lane] + red[3][2][lane] + red[3][3][lane];
        float gi = 1.f / (1.f + __expf(-zi));
        float gf = 1.f / (1.f + __expf(-zf));
        float go = 1.f / (1.f + __expf(-zo));
        float cn = gf * c[j] + gi * zg;
        float ho = h[j];
        float hn = go * cn;
        orders[(size_t)t * Hn + j] = ho;
        h[j] = hn;
        c[j] = cn;
    }
}

extern "C" void kernel_launch(void* const* d_in, const int* in_sizes, int n_in,
                              void* d_out, int out_size, void* d_ws, size_t ws_size,
                              hipStream_t stream) {
    const float* henc = (const float*)d_in[0];
    const float* h0   = (const float*)d_in[1];
    const float* W    = (const float*)d_in[2];
    const float* U    = (const float*)d_in[3];
    const float* bias = (const float*)d_in[4];
    float* out = (float*)d_out;

    const size_t needM = (size_t)Hn * H4 * sizeof(__half);    // 134 MB fp16
    const size_t needX = (size_t)Pn * H4 * sizeof(float);     // 5.3 MB
    const size_t needZ = (size_t)KSPLIT * H4 * sizeof(float); // 4.2 MB (x2)
    const size_t needC = (size_t)Hn * sizeof(float);          // 16 KB (x2)

    char* ws = (char*)d_ws;
    const bool fused = ws_size >= needM + needX + 2 * needZ + 2 * needC;

    if (fused) {
        __half* Mh = (__half*)ws;
        float*  X  = (float*)(ws + needM);
        float*  zp[2];
        zp[0] = (float*)(ws + needM + needX);
        zp[1] = (float*)(ws + needM + needX + needZ);
        float* cb[2];
        cb[0] = (float*)(ws + needM + needX + 2 * needZ);
        cb[1] = cb[0] + Hn;

        xproj_kernel<<<dim3(H4 / 256, (Pn + TT - 1) / TT), 256, 0, stream>>>(henc, W, bias, X);
        init_kernel<<<dim3(Hn / 256), 256, 0, stream>>>(h0, out, cb[0]);
        // step 0: build Mh while computing z0 = h0 @ Mf  (writes zp[0])
        fuse_step0_kernel<<<dim3(CG, KSPLIT), 512, 0, stream>>>(W, U, h0, Mh, zp[0]);

        for (int t = 1; t < Pn - 1; ++t) {   // steps 1..79 (z_80 is never needed)
            step_kernel<<<dim3(CG, KSPLIT), 512, 0, stream>>>(
                Mh, X, zp[(t + 1) & 1], zp[t & 1],
                cb[(t + 1) & 1], cb[t & 1], out, t);
        }
        // orders[80] from zpart of t=79 (zp[1]) and c_79 (cb[1])
        final_gate_kernel<<<dim3(Hn / 64), 256, 0, stream>>>(zp[1], X, cb[1], out);
    } else {
        float* X     = (float*)ws;
        float* zpart = (float*)(ws + needX);
        float* h     = (float*)(ws + needX + needZ);
        float* c     = h + Hn;

        xproj_kernel<<<dim3(H4 / 256, (Pn + TT - 1) / TT), 256, 0, stream>>>(henc, W, bias, X);
        fb_init_kernel<<<dim3(Hn / 256), 256, 0, stream>>>(h0, h, c);
        for (int t = 0; t < Pn; ++t) {
            matvec2_kernel<<<dim3(H4 / 4 / 256, KSPLIT), 256, 0, stream>>>(
                W + (size_t)En * H4, U, h, zpart);
            gate_kernel<<<dim3(Hn / 64), 256, 0, stream>>>(zpart, X, h, c, out, t);
        }
    }
}